// Round 13
// baseline (291.498 us; speedup 1.0000x reference)
//
#include <hip/hip_runtime.h>
#include <hip/hip_fp8.h>
#include <math.h>

#define BATCH   2048
#define NROWS   4096   // 2*BATCH
#define LATENT  2048
#define PROJ    256
#define BN_EPS  1e-5f
#define COS_EPS 1e-8f
#define W1SCALE 32.0f      // W1/W2 pre-scaled into e4m3 normal range
#define W1INV   (1.0f / 32.0f)
#define ZNSCALE 16.0f      // zn components ~N(0,1/16) -> x16 for e4m3
#define SIMSCALE (1.0f / 128.0f)   // s = dotq/128 (16*16 scale / temp 0.5)

typedef float f32x4 __attribute__((ext_vector_type(4)));
typedef long  i64;

__device__ __forceinline__ unsigned char f2fp8(float f) {
    __hip_fp8_e4m3 t(f);
    return (unsigned char)t.__x;
}
__device__ __forceinline__ float fp82f(unsigned char b) {
    __hip_fp8_e4m3 t; t.__x = b;
    return (float)t;
}
__device__ __forceinline__ void gl_lds16(const void* g, void* l) {
    __builtin_amdgcn_global_load_lds(
        (const __attribute__((address_space(1))) void*)g,
        (__attribute__((address_space(3))) void*)l, 16, 0, 0);
}
__device__ __forceinline__ int mix8(int R) {
    return (R & 7) ^ ((R >> 1) & 4);
}
__device__ __forceinline__ float aload(const float* p) {
    return __hip_atomic_load(p, __ATOMIC_RELAXED, __HIP_MEMORY_SCOPE_AGENT);
}

// ---------------------------------------------------------------------------
// Fused convert: h_i,h_j -> fp8 Hq; W1 -> fp8*32 W1q; W2 -> fp8*32 W2q.
// Block 0 zeroes sums|sumsqs|rowsum|counters = 12544 floats.
// ---------------------------------------------------------------------------
#define G1 1048576
#define G2 2097152
#define G3 3145728
#define G4 3276800
__global__ __launch_bounds__(256) void cvt_all_kernel(
    const float* __restrict__ h_i, const float* __restrict__ h_j,
    const float* __restrict__ W1,  const float* __restrict__ W2,
    unsigned char* __restrict__ Hq, unsigned char* __restrict__ W1q,
    unsigned char* __restrict__ W2q, float* __restrict__ zeroacc)
{
    int i = blockIdx.x * 256 + threadIdx.x;
    if (blockIdx.x == 0) {
        #pragma unroll
        for (int u = 0; u < 49; ++u) zeroacc[u * 256 + threadIdx.x] = 0.f;
    }
    if (i >= G4) return;
    if (i < G2) {
        const float* src = (i < G1) ? h_i : h_j;
        int off = (i < G1) ? i : i - G1;
        float4 v = reinterpret_cast<const float4*>(src)[off];
        uchar4 o;
        o.x = f2fp8(v.x); o.y = f2fp8(v.y); o.z = f2fp8(v.z); o.w = f2fp8(v.w);
        reinterpret_cast<uchar4*>(Hq)[i] = o;
    } else if (i < G3) {
        int off = i - G2;
        float4 v = reinterpret_cast<const float4*>(W1)[off];
        uchar4 o;
        o.x = f2fp8(v.x * W1SCALE); o.y = f2fp8(v.y * W1SCALE);
        o.z = f2fp8(v.z * W1SCALE); o.w = f2fp8(v.w * W1SCALE);
        reinterpret_cast<uchar4*>(W1q)[off] = o;
    } else {
        int off = i - G3;
        float4 v = reinterpret_cast<const float4*>(W2)[off];
        uchar4 o;
        o.x = f2fp8(v.x * W1SCALE); o.y = f2fp8(v.y * W1SCALE);
        o.z = f2fp8(v.z * W1SCALE); o.w = f2fp8(v.w * W1SCALE);
        reinterpret_cast<uchar4*>(W2q)[off] = o;
    }
}

// ---------------------------------------------------------------------------
// fp8 MFMA K-loop: BM=128, BN=64, BK=128. acc[4][2]. 4 waves in 2x2.
// ---------------------------------------------------------------------------
template<int KSTRIDE, int KLEN>
__device__ __forceinline__ void fp8_loop(
    const unsigned char* __restrict__ Ab, const unsigned char* __restrict__ Bb,
    unsigned char* As, unsigned char* Bs, f32x4 acc[4][2], int tid)
{
    const int wid = tid >> 6, lane = tid & 63;
    const int mblk = (wid >> 1) * 64, nblk = (wid & 1) * 32;
    const int lr = lane & 15, lk = lane >> 4;
    for (int k0 = 0; k0 < KLEN; k0 += 128) {
        __syncthreads();
        #pragma unroll
        for (int u = 0; u < 4; ++u) {
            int li = u * 256 + tid;
            int r = li >> 3, s = li & 7;
            gl_lds16(Ab + (size_t)r * KSTRIDE + k0 + ((s ^ mix8(r)) * 16), As + li * 16);
        }
        #pragma unroll
        for (int u = 0; u < 2; ++u) {
            int li = u * 256 + tid;
            int r = li >> 3, s = li & 7;
            gl_lds16(Bb + (size_t)r * KSTRIDE + k0 + ((s ^ mix8(r)) * 16), Bs + li * 16);
        }
        __syncthreads();
        i64 af[4][4], bv[2][4];
        #pragma unroll
        for (int i = 0; i < 4; ++i) {
            int R = mblk + i * 16 + lr;
            int mr = mix8(R);
            int base = R * 128 + (lk & 1) * 8;
            #pragma unroll
            for (int t = 0; t < 4; ++t) {
                int g = 2 * t + (lk >> 1);
                af[i][t] = *reinterpret_cast<const i64*>(As + base + ((g ^ mr) << 4));
            }
        }
        #pragma unroll
        for (int j = 0; j < 2; ++j) {
            int R = nblk + j * 16 + lr;
            int mr = mix8(R);
            int base = R * 128 + (lk & 1) * 8;
            #pragma unroll
            for (int t = 0; t < 4; ++t) {
                int g = 2 * t + (lk >> 1);
                bv[j][t] = *reinterpret_cast<const i64*>(Bs + base + ((g ^ mr) << 4));
            }
        }
        #pragma unroll
        for (int t = 0; t < 4; ++t)
            #pragma unroll
            for (int i = 0; i < 4; ++i)
                #pragma unroll
                for (int j = 0; j < 2; ++j)
                    acc[i][j] = __builtin_amdgcn_mfma_f32_16x16x32_fp8_fp8(
                        af[i][t], bv[j][t], acc[i][j], 0, 0, 0);
    }
}

// ---------------------------------------------------------------------------
// GEMM1 (fp8): X[m][n] = sum_k H[m][k]*W1[n][k]  (4096x2048x2048)
// BM=128 x BN=64 -> 1024 blocks (4/CU). Epilogue: raw-X fp8 store + BN stats.
// ---------------------------------------------------------------------------
__global__ __launch_bounds__(256, 4) void gemm1_fp8(
    const unsigned char* __restrict__ Hq, const unsigned char* __restrict__ W1q,
    unsigned char* __restrict__ Xq, float* __restrict__ sums, float* __restrict__ sumsqs)
{
    __shared__ __align__(16) unsigned char As[128 * 128];
    __shared__ __align__(16) unsigned char Bs[64 * 128];
    const int tid = threadIdx.x;
    const int m0 = blockIdx.y * 128, n0 = blockIdx.x * 64;
    f32x4 zero = {0.f, 0.f, 0.f, 0.f};
    f32x4 acc[4][2];
    #pragma unroll
    for (int i = 0; i < 4; ++i) { acc[i][0] = zero; acc[i][1] = zero; }
    fp8_loop<LATENT, LATENT>(Hq + (size_t)m0 * LATENT, W1q + (size_t)n0 * LATENT,
                             As, Bs, acc, tid);
    const int wid = tid >> 6, lane = tid & 63;
    const int mblk = (wid >> 1) * 64, nblk = (wid & 1) * 32;
    const int lr = lane & 15, lq = lane >> 4;
    const int half = m0 >> 11;
    #pragma unroll
    for (int j = 0; j < 2; ++j) {
        float s = 0.f, q = 0.f;
        #pragma unroll
        for (int i = 0; i < 4; ++i)
            #pragma unroll
            for (int r = 0; r < 4; ++r) {
                float v = acc[i][j][r] * W1INV;
                s += v; q += v * v;
                int row = m0 + mblk + i * 16 + lq * 4 + r;
                int col = n0 + nblk + j * 16 + lr;
                Xq[(size_t)row * LATENT + col] = f2fp8(v);   // raw X, ~N(0,1)
            }
        s += __shfl_xor(s, 16, 64);  q += __shfl_xor(q, 16, 64);
        s += __shfl_xor(s, 32, 64);  q += __shfl_xor(q, 32, 64);
        if (lq == 0) {
            int col = n0 + nblk + j * 16 + lr;
            atomicAdd(&sums[half * LATENT + col], s);
            atomicAdd(&sumsqs[half * LATENT + col], q);
        }
    }
}

// ---------------------------------------------------------------------------
// BN+ReLU in-place on fp8 X. One block per row, 8 elems/thread.
// ---------------------------------------------------------------------------
__global__ __launch_bounds__(256) void bnrelu8_kernel(
    unsigned char* __restrict__ Xq, const float* __restrict__ sums,
    const float* __restrict__ sumsqs, const float* __restrict__ gamma,
    const float* __restrict__ beta)
{
    const int row = blockIdx.x;
    const int half = row >> 11;
    const int col = threadIdx.x * 8;
    size_t idx = (size_t)row * LATENT + col;
    uchar4 a = *reinterpret_cast<const uchar4*>(Xq + idx);
    uchar4 b = *reinterpret_cast<const uchar4*>(Xq + idx + 4);
    uchar4 oa, ob;
    #pragma unroll
    for (int u = 0; u < 8; ++u) {
        int c = col + u;
        int g = half * LATENT + c;
        float mu  = sums[g] * (1.0f / BATCH);
        float var = sumsqs[g] * (1.0f / BATCH) - mu * mu;
        float sc = gamma[c] * rsqrtf(var + BN_EPS);
        float sh = beta[c] - mu * sc;
        unsigned char x = (u < 4) ? ((const unsigned char*)&a)[u] : ((const unsigned char*)&b)[u - 4];
        unsigned char o = f2fp8(fmaxf(fmaf(fp82f(x), sc, sh), 0.f));
        if (u < 4) ((unsigned char*)&oa)[u] = o; else ((unsigned char*)&ob)[u - 4] = o;
    }
    *reinterpret_cast<uchar4*>(Xq + idx) = oa;
    *reinterpret_cast<uchar4*>(Xq + idx + 4) = ob;
}

// ---------------------------------------------------------------------------
// GEMM2 (fp8) split-K=4 + last-block rownorm: 512 blocks (4 n x 32 m x 4 kc).
// Partials fp32. The 16th block finishing an m-group sums its 4 kc x 4 n
// partials (agent-scope loads), adds b2, L2-normalizes, writes fp8 ZNq.
// ---------------------------------------------------------------------------
__global__ __launch_bounds__(256) void gemm2_fp8(
    const unsigned char* __restrict__ Xq, const unsigned char* __restrict__ W2q,
    float* __restrict__ Zp, const float* __restrict__ b2,
    unsigned char* __restrict__ ZNq, int* __restrict__ cnt)
{
    __shared__ __align__(16) unsigned char As[128 * 128];
    __shared__ __align__(16) unsigned char Bs[64 * 128];
    __shared__ int iswin;
    const int tid = threadIdx.x;
    const int m0 = blockIdx.y * 128, n0 = blockIdx.x * 64, kc = blockIdx.z;
    f32x4 zero = {0.f, 0.f, 0.f, 0.f};
    f32x4 acc[4][2];
    #pragma unroll
    for (int i = 0; i < 4; ++i) { acc[i][0] = zero; acc[i][1] = zero; }
    fp8_loop<LATENT, 512>(Xq + (size_t)m0 * LATENT + kc * 512,
                          W2q + (size_t)n0 * LATENT + kc * 512, As, Bs, acc, tid);
    float* Zk = Zp + (size_t)kc * NROWS * PROJ;
    const int wid = tid >> 6, lane = tid & 63;
    const int mblk = (wid >> 1) * 64, nblk = (wid & 1) * 32;
    const int lr = lane & 15, lq = lane >> 4;
    #pragma unroll
    for (int i = 0; i < 4; ++i)
        #pragma unroll
        for (int j = 0; j < 2; ++j)
            #pragma unroll
            for (int r = 0; r < 4; ++r) {
                int row = m0 + mblk + i * 16 + lq * 4 + r;
                int col = n0 + nblk + j * 16 + lr;
                Zk[(size_t)row * PROJ + col] = acc[i][j][r] * W1INV;
            }
    // last-of-16 for this m-group does the rownorm epilogue
    __threadfence();
    if (tid == 0) {
        int old = atomicAdd(&cnt[blockIdx.y], 1);
        iswin = (old == 15);
    }
    __syncthreads();
    if (!iswin) return;
    __threadfence();
    const int wave = tid >> 6, ln = tid & 63;
    for (int rr = wave; rr < 128; rr += 4) {
        int row = m0 + rr;
        float v[4];
        float sq = 0.f;
        #pragma unroll
        for (int i = 0; i < 4; ++i) {
            int col = ln + i * 64;
            float t = b2[col];
            #pragma unroll
            for (int c = 0; c < 4; ++c)
                t += aload(&Zp[(size_t)c * NROWS * PROJ + (size_t)row * PROJ + col]);
            v[i] = t;
            sq += t * t;
        }
        #pragma unroll
        for (int off = 32; off > 0; off >>= 1) sq += __shfl_xor(sq, off, 64);
        float inv = ZNSCALE / fmaxf(sqrtf(sq), COS_EPS);
        #pragma unroll
        for (int i = 0; i < 4; ++i)
            ZNq[(size_t)row * PROJ + ln + i * 64] = f2fp8(v[i] * inv);
    }
}

// ---------------------------------------------------------------------------
// sim tiles (fp8), upper-triangle only, K=256 staged in ONE shot (1 barrier).
// Off-diag tiles contribute row AND column sums. 528th finishing block runs
// the loss reduction (agent-scope loads).
// ---------------------------------------------------------------------------
__global__ __launch_bounds__(256) void simlse_fp8(
    const unsigned char* __restrict__ ZNq, float* __restrict__ rowsum,
    float* __restrict__ dgA, float* __restrict__ posA,
    int* __restrict__ cnt, float* __restrict__ out)
{
    if (blockIdx.x < blockIdx.y) return;   // symmetry: only tj >= ti
    __shared__ __align__(16) unsigned char As[128 * 256];
    __shared__ __align__(16) unsigned char Bs[128 * 256];
    __shared__ int iswin;
    const int tid = threadIdx.x;
    const int r0 = blockIdx.y * 128, j0 = blockIdx.x * 128;
    const bool offdiag = (j0 != r0);
    const unsigned char* Ab = ZNq + (size_t)r0 * PROJ;
    const unsigned char* Bb = ZNq + (size_t)j0 * PROJ;
    #pragma unroll
    for (int u = 0; u < 8; ++u) {
        int li = u * 256 + tid;
        int r = li >> 4, s = li & 15;
        gl_lds16(Ab + (size_t)r * PROJ + ((s ^ (r & 15)) * 16), As + li * 16);
    }
    #pragma unroll
    for (int u = 0; u < 8; ++u) {
        int li = u * 256 + tid;
        int r = li >> 4, s = li & 15;
        gl_lds16(Bb + (size_t)r * PROJ + ((s ^ (r & 15)) * 16), Bs + li * 16);
    }
    __syncthreads();
    const int wid = tid >> 6, lane = tid & 63;
    const int mblk = (wid >> 1) * 64, nblk = (wid & 1) * 64;
    const int lr = lane & 15, lk = lane >> 4;
    f32x4 zero = {0.f, 0.f, 0.f, 0.f};
    f32x4 acc[4][4];
    #pragma unroll
    for (int i = 0; i < 4; ++i)
        #pragma unroll
        for (int j = 0; j < 4; ++j) acc[i][j] = zero;
    #pragma unroll
    for (int t = 0; t < 8; ++t) {
        int g = 2 * t + (lk >> 1);
        i64 af[4], bv[4];
        #pragma unroll
        for (int i = 0; i < 4; ++i) {
            int R = mblk + i * 16 + lr;
            af[i] = *reinterpret_cast<const i64*>(As + R * 256 + ((g ^ (R & 15)) << 4) + (lk & 1) * 8);
        }
        #pragma unroll
        for (int j = 0; j < 4; ++j) {
            int R = nblk + j * 16 + lr;
            bv[j] = *reinterpret_cast<const i64*>(Bs + R * 256 + ((g ^ (R & 15)) << 4) + (lk & 1) * 8);
        }
        #pragma unroll
        for (int i = 0; i < 4; ++i)
            #pragma unroll
            for (int j = 0; j < 4; ++j)
                acc[i][j] = __builtin_amdgcn_mfma_f32_16x16x32_fp8_fp8(af[i], bv[j], acc[i][j], 0, 0, 0);
    }
    const int lq = lane >> 4;
    float tcol[4] = {0.f, 0.f, 0.f, 0.f};
    #pragma unroll
    for (int i = 0; i < 4; ++i)
        #pragma unroll
        for (int r = 0; r < 4; ++r) {
            int R = r0 + mblk + i * 16 + lq * 4 + r;
            int P = (R < BATCH) ? R + BATCH : R - BATCH;
            float t = 0.f;
            #pragma unroll
            for (int j = 0; j < 4; ++j) {
                int J = j0 + nblk + j * 16 + lr;
                float s = acc[i][j][r] * SIMSCALE;
                float e = __expf(s);
                t += e;
                tcol[j] += e;
                if (J == R) dgA[R] = e;                    // diag tiles only
                if (J == P) { posA[R] = s; posA[J] = s; }  // s[R,P]==s[P,R]
            }
            t += __shfl_xor(t, 1, 64);
            t += __shfl_xor(t, 2, 64);
            t += __shfl_xor(t, 4, 64);
            t += __shfl_xor(t, 8, 64);
            if (lr == 0) atomicAdd(&rowsum[R], t);
        }
    if (offdiag) {
        #pragma unroll
        for (int j = 0; j < 4; ++j) {
            float c = tcol[j];
            c += __shfl_xor(c, 16, 64);
            c += __shfl_xor(c, 32, 64);
            if (lq == 0) atomicAdd(&rowsum[j0 + nblk + j * 16 + lr], c);
        }
    }
    // last-of-528 runs the loss reduction
    __threadfence();
    if (tid == 0) {
        int old = atomicAdd(cnt, 1);
        iswin = (old == 527);
    }
    __syncthreads();
    if (!iswin) return;
    __threadfence();
    float* red = (float*)As;   // reuse LDS
    float s = 0.f;
    for (int r = tid; r < NROWS; r += 256)
        s += logf(aload(&rowsum[r]) - aload(&dgA[r])) - aload(&posA[r]);
    red[tid] = s;
    __syncthreads();
    for (int off = 128; off > 0; off >>= 1) {
        if (tid < off) red[tid] += red[tid + off];
        __syncthreads();
    }
    if (tid == 0) out[0] = red[0] * (1.0f / NROWS);
}

// ---------------------------------------------------------------------------
extern "C" void kernel_launch(void* const* d_in, const int* in_sizes, int n_in,
                              void* d_out, int out_size, void* d_ws, size_t ws_size,
                              hipStream_t stream)
{
    const float* h_i   = (const float*)d_in[0];
    const float* h_j   = (const float*)d_in[1];
    const float* W1    = (const float*)d_in[2];
    const float* gamma = (const float*)d_in[3];
    const float* beta  = (const float*)d_in[4];
    const float* W2    = (const float*)d_in[5];
    const float* b2    = (const float*)d_in[6];
    float* out = (float*)d_out;

    // workspace (~39 MB). Zeroed prefix: sums|sumsqs|rowsum|cnt = 12544 floats.
    float* sums   = (float*)d_ws;                            // 4096
    float* sumsqs = sums + 2 * LATENT;                       // 4096
    float* rowsum = sumsqs + 2 * LATENT;                     // 4096
    int*   cnt    = (int*)(rowsum + NROWS);                  // 256 (32 gemm2 + 1 simlse)
    float* dgA    = (float*)(cnt + 256);                     // 4096
    float* posA   = dgA + NROWS;                             // 4096
    float* Zp     = posA + NROWS;                            // 4 * 4096*256 fp32
    unsigned char* Hq  = (unsigned char*)(Zp + (size_t)4 * NROWS * PROJ); // 4096*2048 fp8
    unsigned char* W1q = Hq + (size_t)NROWS * LATENT;        // 2048*2048 fp8
    unsigned char* W2q = W1q + (size_t)LATENT * LATENT;      // 256*2048 fp8
    unsigned char* Xq  = W2q + (size_t)PROJ * LATENT;        // 4096*2048 fp8
    unsigned char* ZNq = Xq + (size_t)NROWS * LATENT;        // 4096*256 fp8

    cvt_all_kernel<<<(G4 + 255) / 256, 256, 0, stream>>>(h_i, h_j, W1, W2, Hq, W1q, W2q, sums);
    gemm1_fp8<<<dim3(LATENT / 64, NROWS / 128), 256, 0, stream>>>(Hq, W1q, Xq, sums, sumsqs);
    bnrelu8_kernel<<<NROWS, 256, 0, stream>>>(Xq, sums, sumsqs, gamma, beta);
    gemm2_fp8<<<dim3(PROJ / 64, NROWS / 128, 4), 256, 0, stream>>>(Xq, W2q, Zp, b2, ZNq, cnt);
    simlse_fp8<<<dim3(NROWS / 128, NROWS / 128), 256, 0, stream>>>(ZNq, rowsum, dgA, posA, cnt + 32, out);
}